// Round 18
// baseline (1133.644 us; speedup 1.0000x reference)
//
#include <hip/hip_runtime.h>

// ---------------- dims ----------------
#define BB 1024
#define NN 9
#define LL 81            // 81 cells
#define DD 512
#define HH 8
#define EE 64
#define FF 2048
#define MM (BB*LL)       // 82944 rows
#define N3 (3*DD)        // 1536

typedef unsigned short u16;
typedef __bf16 bf16x8 __attribute__((ext_vector_type(8)));
typedef float f32x4 __attribute__((ext_vector_type(4)));
typedef unsigned short u16x8 __attribute__((ext_vector_type(8)));

__device__ __forceinline__ float bf2f(u16 u) {
    return __uint_as_float(((unsigned int)u) << 16);
}
__device__ __forceinline__ u16 f2bf(float f) {
    unsigned int u = __float_as_uint(f);
    unsigned int r = u + 0x7fffu + ((u >> 16) & 1u);
    return (u16)(r >> 16);
}
// tanh-form GELU via manual exp-based tanh (~10 VALU ops; r10-proven)
__device__ __forceinline__ float gelu_fast(float x) {
    float u = 0.7978845608f * x * fmaf(0.044715f * x, x, 1.0f);
    float e = __expf(2.0f * u);
    float t = 1.0f - 2.0f / (e + 1.0f);
    return 0.5f * x * (1.0f + t);
}

// async global->LDS, 16B per lane
#define GL16(g, l) __builtin_amdgcn_global_load_lds( \
    (const __attribute__((address_space(1))) void*)(g), \
    (__attribute__((address_space(3))) void*)(l), 16, 0, 0)

#define SB0 __builtin_amdgcn_sched_barrier(0)

// ---------------- fused prologue: LN1 (blocks 0..20735) + 4 weight transposes ----------------
__global__ __launch_bounds__(256) void prep_k(
    const float* __restrict__ src, const float* __restrict__ g1,
    const float* __restrict__ beta1, u16* __restrict__ xln,
    const float* __restrict__ w_qkv, u16* __restrict__ wqkvt,
    const float* __restrict__ w_out, u16* __restrict__ woutt,
    const float* __restrict__ w_ff1, u16* __restrict__ wff1t,
    const float* __restrict__ w_ff2, u16* __restrict__ wff2t) {
    const int tid = threadIdx.x;
    int ib = blockIdx.x;
    if (ib < MM / 4) {
        // ---- LN1: 4 rows per block, one wave per 512-row ----
        int row = ib * 4 + (tid >> 6);
        int lane = tid & 63;
        const float4* xp = (const float4*)(src + (long)row * DD);
        float4 a = xp[lane * 2], b = xp[lane * 2 + 1];
        float s  = a.x + a.y + a.z + a.w + b.x + b.y + b.z + b.w;
        float sq = a.x*a.x + a.y*a.y + a.z*a.z + a.w*a.w
                 + b.x*b.x + b.y*b.y + b.z*b.z + b.w*b.w;
#pragma unroll
        for (int off = 1; off < 64; off <<= 1) {
            s  += __shfl_xor(s, off);
            sq += __shfl_xor(sq, off);
        }
        float mean = s * (1.0f / 512.0f);
        float var  = sq * (1.0f / 512.0f) - mean * mean;
        float rstd = rsqrtf(var + 1e-5f);
        const float4* gp = (const float4*)(g1 + lane * 8);
        const float4* bp = (const float4*)(beta1 + lane * 8);
        float4 g0 = gp[0], g1v = gp[1], b0 = bp[0], b1v = bp[1];
        float xv[8] = {a.x,a.y,a.z,a.w,b.x,b.y,b.z,b.w};
        float gv[8] = {g0.x,g0.y,g0.z,g0.w,g1v.x,g1v.y,g1v.z,g1v.w};
        float bv[8] = {b0.x,b0.y,b0.z,b0.w,b1v.x,b1v.y,b1v.z,b1v.w};
        u16x8 ov;
#pragma unroll
        for (int j = 0; j < 8; ++j)
            ov[j] = f2bf((xv[j] - mean) * rstd * gv[j] + bv[j]);
        *(u16x8*)(xln + (long)row * DD + lane * 8) = ov;
        return;
    }
    // ---- weight transpose + fp32->bf16: W (KxN) -> Wt (NxK) ----
    ib -= MM / 4;
    const float* W; u16* Wt; int K, N;
    if (ib < 768)        { W = w_qkv; Wt = wqkvt; K = DD; N = N3; }
    else if (ib < 1024)  { ib -= 768;  W = w_out; Wt = woutt; K = DD; N = DD; }
    else if (ib < 2048)  { ib -= 1024; W = w_ff1; Wt = wff1t; K = DD; N = FF; }
    else                 { ib -= 2048; W = w_ff2; Wt = wff2t; K = FF; N = DD; }
    __shared__ float t[32][33];
    const int nbx = N / 32;
    const int n0 = (ib % nbx) * 32, k0 = (ib / nbx) * 32;
    const int tx = tid & 31, ty = tid >> 5;  // 32 x 8
#pragma unroll
    for (int i = 0; i < 32; i += 8)
        t[ty + i][tx] = W[(long)(k0 + ty + i) * N + n0 + tx];
    __syncthreads();
#pragma unroll
    for (int i = 0; i < 32; i += 8)
        Wt[(long)(n0 + ty + i) * K + k0 + tx] = f2bf(t[tx][ty + i]);
}

// ---------------- layernorm bf16-in -> bf16 out ----------------
__global__ __launch_bounds__(256) void layernorm_b(const u16* __restrict__ X,
                                                   const float* __restrict__ g,
                                                   const float* __restrict__ be,
                                                   u16* __restrict__ Y) {
    int row = blockIdx.x * 4 + (threadIdx.x >> 6);
    int lane = threadIdx.x & 63;
    u16x8 xr = *(const u16x8*)(X + (long)row * DD + lane * 8);
    float xv[8];
#pragma unroll
    for (int j = 0; j < 8; ++j) xv[j] = bf2f(xr[j]);
    float s = 0.0f, sq = 0.0f;
#pragma unroll
    for (int j = 0; j < 8; ++j) { s += xv[j]; sq += xv[j] * xv[j]; }
#pragma unroll
    for (int off = 1; off < 64; off <<= 1) {
        s  += __shfl_xor(s, off);
        sq += __shfl_xor(sq, off);
    }
    float mean = s * (1.0f / 512.0f);
    float var  = sq * (1.0f / 512.0f) - mean * mean;
    float rstd = rsqrtf(var + 1e-5f);
    const float4* gp = (const float4*)(g + lane * 8);
    const float4* bp = (const float4*)(be + lane * 8);
    float4 g0 = gp[0], g1v = gp[1], b0 = bp[0], b1v = bp[1];
    float gv[8] = {g0.x,g0.y,g0.z,g0.w,g1v.x,g1v.y,g1v.z,g1v.w};
    float bv[8] = {b0.x,b0.y,b0.z,b0.w,b1v.x,b1v.y,b1v.z,b1v.w};
    u16x8 ov;
#pragma unroll
    for (int j = 0; j < 8; ++j)
        ov[j] = f2bf((xv[j] - mean) * rstd * gv[j] + bv[j]);
    *(u16x8*)(Y + (long)row * DD + lane * 8) = ov;
}

// ---------------- GEMM 256x128 (r12/r16-proven): all 6 GEMM dispatches ----------------
// Block 256x128, 4 waves of 128x64 (16x16x32 MFMA). BK=32, 3-buffer
// stage-2-ahead, ONE barrier per K-step, counted vmcnt(6), conflict-free
// both-sides slot swizzle, XCD-chunked block swizzle, LDS-bounce epilogues.
// F32_PART: store partial fp32 (ff2 chunk 0). F32_FINAL: out = gemm + bias +
// fp32 partial (RMW) + bf16 residual (ff2 chunk 1).
// NOTE: (256,2) only -- (256,3) spills the 128-AGPR accumulator (r11 disaster).
enum { EPI_BF16_BIAS = 0, EPI_BF16_RESID = 1, EPI_BF16_GELU = 2,
       EPI_F32_PART = 3, EPI_F32_FINAL = 4 };

template <int EPI>
__global__ __launch_bounds__(256, 2) void gemm_bt(
    const u16* __restrict__ A, int lda,
    const u16* __restrict__ Bt, int ldb,
    const float* __restrict__ bias,   // may be null
    const float* __restrict__ residF, // EPI_BF16_RESID: fp32 residual
    const u16* __restrict__ residB,   // EPI_F32_FINAL: bf16 residual
    u16* __restrict__ outB, float* __restrict__ outF,
    int N, int K, int nbn) {
    __shared__ u16 smem[36864];            // 72KB: A 3x16KB + B 3x8KB; epilogue aliases
    u16* const Asb = smem;
    u16* const Bsb = smem + 24576;
    const int tid = threadIdx.x;
    const int lane = tid & 63;
    const int w = tid >> 6;
    const int wr = w >> 1, wc = w & 1;     // 2x2 waves; wave tile 128x64

    // bijective XCD-chunked swizzle (all launches have gridDim.x % 8 == 0)
    const int cpx = gridDim.x >> 3;
    const int bid = (blockIdx.x & 7) * cpx + (blockIdx.x >> 3);
    const int bm = bid / nbn, bn = bid % nbn;
    const long Arow0 = (long)bm * 256;
    const long Brow0 = (long)bn * 128;

    auto stage = [&](int buf, int kt) {
        const u16* abase = A + Arow0 * (long)lda + (long)kt * 32;
        const u16* bbase = Bt + Brow0 * (long)ldb + (long)kt * 32;
#pragma unroll
        for (int u = 0; u < 4; ++u) {
            const int c = tid + u * 256;       // 1024 A-chunks of 16B
            const int row = c >> 2;
            const int col = ((c & 3) ^ ((row >> 1) & 3)) * 8;
            GL16(abase + (long)row * lda + col, Asb + buf * 8192 + c * 8);
        }
#pragma unroll
        for (int u = 0; u < 2; ++u) {
            const int c = tid + u * 256;       // 512 B-chunks of 16B
            const int row = c >> 2;
            const int col = ((c & 3) ^ ((row >> 1) & 3)) * 8;
            GL16(bbase + (long)row * ldb + col, Bsb + buf * 4096 + c * 8);
        }
    };

    f32x4 acc[8][4] = {};
    const int fr = lane & 15;
    const int s8 = lane >> 4;
    const int sl = (s8 ^ ((fr >> 1) & 3)) * 8;  // conflict-free swizzled 16B slot

    const int nk = K / 32;
    stage(0, 0); stage(1, 1);              // 12 GL16/thread in flight

    int cur = 0;
    for (int kt = 0; kt < nk; ++kt) {
        if (kt + 1 < nk) { asm volatile("s_waitcnt vmcnt(6)" ::: "memory"); }
        else             { asm volatile("s_waitcnt vmcnt(0)" ::: "memory"); }
        SB0;
        __builtin_amdgcn_s_barrier();      // publishes buf[cur]; orders prior reads
        SB0;

        bf16x8 af[8], bb[4];
        const u16* Ab = Asb + cur * 8192;
        const u16* Bb = Bsb + cur * 4096;
#pragma unroll
        for (int mt = 0; mt < 8; ++mt)
            af[mt] = *(const bf16x8*)(Ab + (wr * 128 + mt * 16 + fr) * 32 + sl);
#pragma unroll
        for (int nt = 0; nt < 4; ++nt)
            bb[nt] = *(const bf16x8*)(Bb + (wc * 64 + nt * 16 + fr) * 32 + sl);

        if (kt + 2 < nk) {                 // stage into buf last read at iter kt-1
            int nb = cur + 2; if (nb >= 3) nb -= 3;
            stage(nb, kt + 2);
        }

        asm volatile("s_waitcnt lgkmcnt(0)" ::: "memory");
        SB0;                               // rule #18: keep MFMAs below the wait
#pragma unroll
        for (int mt = 0; mt < 8; ++mt)
#pragma unroll
            for (int nt = 0; nt < 4; ++nt)
                acc[mt][nt] = __builtin_amdgcn_mfma_f32_16x16x32_bf16(af[mt], bb[nt], acc[mt][nt], 0, 0, 0);
        cur = cur + 1; if (cur == 3) cur = 0;
    }

    if (EPI == EPI_BF16_BIAS || EPI == EPI_BF16_GELU || EPI == EPI_BF16_RESID) {
        __builtin_amdgcn_s_barrier();      // all MFMA frag reads done before aliasing
        // bf16 LDS-bounce epilogue: 256x128 tile, pad stride 132, 16B stores
        u16 (*eps)[132] = (u16(*)[132])smem;
#pragma unroll
        for (int nt = 0; nt < 4; ++nt) {
            const int cl = wc * 64 + nt * 16 + fr;
            const float bv = bias ? bias[bn * 128 + cl] : 0.0f;
#pragma unroll
            for (int mt = 0; mt < 8; ++mt) {
                const int rl = wr * 128 + mt * 16 + s8 * 4;
#pragma unroll
                for (int q = 0; q < 4; ++q) {
                    float v = acc[mt][nt][q] + bv;
                    if (EPI == EPI_BF16_GELU) v = gelu_fast(v);
                    if (EPI == EPI_BF16_RESID)
                        v += residF[(Arow0 + rl + q) * (long)N + bn * 128 + cl];
                    eps[rl + q][cl] = f2bf(v);
                }
            }
        }
        __syncthreads();
#pragma unroll
        for (int u = 0; u < 16; ++u) {
            const int i = u * 256 + tid;
            const int row = i >> 4, cc = (i & 15) * 8;
            u16x8 vv = *(const u16x8*)&eps[row][cc];
            *(u16x8*)(outB + (Arow0 + row) * (long)N + bn * 128 + cc) = vv;
        }
    } else {  // fp32 LDS-bounce epilogues (two 128-row halves, 128x132 f32 <= 72KB)
        float (*epf)[132] = (float(*)[132])smem;
#pragma unroll
        for (int h = 0; h < 2; ++h) {
            __syncthreads();               // prior reads (K-loop / prev half) done
            if (wr == h) {
#pragma unroll
                for (int nt = 0; nt < 4; ++nt) {
                    const int cl = wc * 64 + nt * 16 + fr;
                    const float bv = bias ? bias[bn * 128 + cl] : 0.0f;
#pragma unroll
                    for (int mt = 0; mt < 8; ++mt) {
                        const int rl = mt * 16 + s8 * 4;    // local row in half
#pragma unroll
                        for (int q = 0; q < 4; ++q)
                            epf[rl + q][cl] = acc[mt][nt][q] + bv;
                    }
                }
            }
            __syncthreads();
            // coalesced float4 stores: 128 rows x 32 chunks of 16B
#pragma unroll
            for (int u = 0; u < 16; ++u) {
                const int i = u * 256 + tid;
                const int row = i >> 5, cc = (i & 31) * 4;
                const long gr = (Arow0 + h * 128 + row) * (long)N + bn * 128 + cc;
                float4 vv = *(const float4*)&epf[row][cc];
                if (EPI == EPI_F32_FINAL) {
                    float4 pp = *(const float4*)(outF + gr);      // fp32 partial
                    ushort4 rb = *(const ushort4*)(residB + gr);  // bf16 xb
                    vv.x += pp.x + bf2f(rb.x); vv.y += pp.y + bf2f(rb.y);
                    vv.z += pp.z + bf2f(rb.z); vv.w += pp.w + bf2f(rb.w);
                }
                *(float4*)(outF + gr) = vv;
            }
        }
    }
}

// ---------------- factorized attention via MFMA: one block per (b, h) ----------------
// qkv: (B*L, 1536) bf16. y is written IN-PLACE into the q-slots (stride N3).
__global__ __launch_bounds__(256) void attn_k(u16* __restrict__ qkv) {
    __shared__ u16 S[96][104];    // bf16 scores
    __shared__ u16 Wm[96][104];   // bf16 combined softmax weights (cols 81..95 stay 0)
    __shared__ u16 Vt[64][104];   // V transposed: Vt[e][cell]
    const int bh = blockIdx.x;
    const int b = bh >> 3, h = bh & 7;
    u16* qbase = qkv + (long)b * LL * N3 + h * EE;
    const u16* kbase = qbase + DD;
    const u16* vbase = qbase + 2 * DD;
    const int tid = threadIdx.x;
    const int lane = tid & 63;
    const int w = tid >> 6;
    const int fr = lane & 15, s8 = lane >> 4;

    // phase 0a: zero Wm, zero Vt pad cols, scatter V -> Vt
    {
        u16x8 z = {};
        u16* wp = &Wm[0][0];
        for (int i = tid; i < (96 * 104) / 8; i += 256)
            *(u16x8*)(wp + i * 8) = z;
        for (int i = tid; i < 64 * 16; i += 256) {
            int e = i >> 4, c = i & 15;
            if (c < 15) Vt[e][81 + c] = 0;
        }
        for (int i = tid; i < 81 * 16; i += 256) {
            int cell = i >> 4, e0 = (i & 15) * 4;
            ushort4 v = *(const ushort4*)(vbase + (long)cell * N3 + e0);
            Vt[e0][cell] = v.x; Vt[e0 + 1][cell] = v.y;
            Vt[e0 + 2][cell] = v.z; Vt[e0 + 3][cell] = v.w;
        }
    }

    // phase 0b: QK^T -> S. 36 tiles of 16x16, K = 64; frags straight from global.
    for (int i = 0; i < 9; ++i) {
        const int tile = w + 4 * i;
        const int qt = tile / 6, kt = tile % 6;
        int qc = qt * 16 + fr; if (qc > 80) qc = 80;
        int kc = kt * 16 + fr; if (kc > 80) kc = 80;
        const u16* qp = qbase + (long)qc * N3 + s8 * 8;
        const u16* kp = kbase + (long)kc * N3 + s8 * 8;
        bf16x8 a0 = *(const bf16x8*)qp;
        bf16x8 a1 = *(const bf16x8*)(qp + 32);
        bf16x8 b0 = *(const bf16x8*)kp;
        bf16x8 b1 = *(const bf16x8*)(kp + 32);
        f32x4 acc = {};
        acc = __builtin_amdgcn_mfma_f32_16x16x32_bf16(a0, b0, acc, 0, 0, 0);
        acc = __builtin_amdgcn_mfma_f32_16x16x32_bf16(a1, b1, acc, 0, 0, 0);
#pragma unroll
        for (int q = 0; q < 4; ++q)
            S[qt * 16 + s8 * 4 + q][kt * 16 + fr] = f2bf(acc[q]);
    }
    __syncthreads();

    // phase 1: 3 softmaxes per query row, scatter-add into dense Wm row
    if (tid < 81) {
        const int q = tid;
        const int r = q / 9, c = q % 9;
#pragma unroll
        for (int t = 0; t < 3; ++t) {
            int mm[9];
            if (t == 0) {
#pragma unroll
                for (int j = 0; j < 9; ++j) mm[j] = r * 9 + j;
            } else if (t == 1) {
#pragma unroll
                for (int j = 0; j < 9; ++j) mm[j] = j * 9 + c;
            } else {
                const int br = (r / 3) * 3, bc = (c / 3) * 3;
#pragma unroll
                for (int j = 0; j < 9; ++j) mm[j] = (br + j / 3) * 9 + bc + j % 3;
            }
            float sc[9], mx = -1e30f;
#pragma unroll
            for (int j = 0; j < 9; ++j) {
                sc[j] = bf2f(S[q][mm[j]]) * 0.125f;
                mx = fmaxf(mx, sc[j]);
            }
            float sum = 0.0f;
#pragma unroll
            for (int j = 0; j < 9; ++j) { sc[j] = __expf(sc[j] - mx); sum += sc[j]; }
            const float inv = 1.0f / (3.0f * sum);
#pragma unroll
            for (int j = 0; j < 9; ++j) {
                u16* p = &Wm[q][mm[j]];
                *p = f2bf(bf2f(*p) + sc[j] * inv);
            }
        }
    }
    __syncthreads();

    // phase 2: Y^T = Vt(e,cell) @ Wm^T(cell,q); 8B stores into q-slots (stride N3)
    for (int i = 0; i < 6; ++i) {
        const int tile = w + 4 * i;
        const int qt = tile % 6, et = tile / 6;
        f32x4 acc = {};
#pragma unroll
        for (int kc = 0; kc < 3; ++kc) {
            bf16x8 a  = *(const bf16x8*)&Vt[et * 16 + fr][kc * 32 + s8 * 8];
            bf16x8 bf = *(const bf16x8*)&Wm[qt * 16 + fr][kc * 32 + s8 * 8];
            acc = __builtin_amdgcn_mfma_f32_16x16x32_bf16(a, bf, acc, 0, 0, 0);
        }
        const int q = qt * 16 + fr;
        if (q < 81) {
            ushort4 o;
            o.x = f2bf(acc[0]); o.y = f2bf(acc[1]);
            o.z = f2bf(acc[2]); o.w = f2bf(acc[3]);
            *(ushort4*)(qbase + (long)q * N3 + et * 16 + s8 * 4) = o;
        }
    }
}

// ---------------- launch ----------------
extern "C" void kernel_launch(void* const* d_in, const int* in_sizes, int n_in,
                              void* d_out, int out_size, void* d_ws, size_t ws_size,
                              hipStream_t stream) {
    const float* src    = (const float*)d_in[0];
    const float* w_qkv  = (const float*)d_in[1];
    const float* b_qkv  = (const float*)d_in[2];
    const float* w_out  = (const float*)d_in[3];
    const float* b_out  = (const float*)d_in[4];
    const float* g1     = (const float*)d_in[5];
    const float* beta1  = (const float*)d_in[6];
    const float* g2     = (const float*)d_in[7];
    const float* beta2  = (const float*)d_in[8];
    const float* w_ff1  = (const float*)d_in[9];
    const float* b_ff1  = (const float*)d_in[10];
    const float* w_ff2  = (const float*)d_in[11];
    const float* b_ff2  = (const float*)d_in[12];
    float* out = (float*)d_out;

    // workspace layout (bytes), all 256-aligned
    char* ws = (char*)d_ws;
    u16* wqkvt = (u16*)(ws + 0);                         // 1536x512 bf16
    u16* woutt = (u16*)(ws + 1572864);                   // 512x512
    u16* wff1t = (u16*)(ws + 2097152);                   // 2048x512
    u16* wff2t = (u16*)(ws + 4194304);                   // 512x2048
    u16* bufA  = (u16*)(ws + 6291456);                   // M x 512 bf16: xln -> xb
    u16* bufB  = (u16*)(ws + 6291456 + 84934656ULL);     // M x 1536 bf16: qkv/y -> hln + h1c
    u16* hln   = bufB;                                   // M x 512 bf16 (LN2 out)
    u16* h1c   = bufB + (size_t)MM * DD;                 // M x 1024 bf16 (per-F-chunk GELU)

    const int nbm = MM / 256;        // 324

    // 1) fused prologue: LN1 (20736 blocks) + all 4 weight transposes (3072 blocks)
    prep_k<<<MM / 4 + 3072, 256, 0, stream>>>(
        src, g1, beta1, bufA,
        w_qkv, wqkvt, w_out, woutt, w_ff1, wff1t, w_ff2, wff2t);

    // 2) qkv = xln @ Wqkv + b  (bf16 out, bufB)
    gemm_bt<EPI_BF16_BIAS><<<nbm * (N3 / 128), 256, 0, stream>>>(
        bufA, DD, wqkvt, DD, b_qkv, nullptr, nullptr, bufB, nullptr, N3, DD, N3 / 128);

    // 3) factorized attention; y overwrites the q-slots of bufB
    attn_k<<<BB * HH, 256, 0, stream>>>(bufB);

    // 4) xb = y @ Wout + b_out + src  (bf16, bufA; y read from bufB with lda=1536)
    gemm_bt<EPI_BF16_RESID><<<nbm * (DD / 128), 256, 0, stream>>>(
        bufB, N3, woutt, DD, b_out, src, nullptr, bufA, nullptr, DD, DD, DD / 128);

    // 5) LN2: xb -> hln (bufB head; qkv fully dead now)
    layernorm_b<<<MM / 4, 256, 0, stream>>>(bufA, g2, beta2, hln);

    // 6) FFN split by F=1024 chunks over FULL M (ff2 grid 2592 -> ~96% residency):
    //    c0: h1c = gelu(hln@W1c0 + b1c0);  out  = h1c@W2c0            (fp32 partial)
    //    c1: h1c = gelu(hln@W1c1 + b1c1);  out += h1c@W2c1 + b2 + xb  (final)
    for (int c = 0; c < 2; ++c) {
        gemm_bt<EPI_BF16_GELU><<<nbm * (1024 / 128), 256, 0, stream>>>(
            hln, DD, wff1t + (size_t)c * 1024 * DD, DD, b_ff1 + c * 1024, nullptr,
            nullptr, h1c, nullptr, 1024, DD, 1024 / 128);
        if (c == 0)
            gemm_bt<EPI_F32_PART><<<nbm * (DD / 128), 256, 0, stream>>>(
                h1c, 1024, wff2t, FF, nullptr, nullptr, nullptr,
                nullptr, out, DD, 1024, DD / 128);
        else
            gemm_bt<EPI_F32_FINAL><<<nbm * (DD / 128), 256, 0, stream>>>(
                h1c, 1024, wff2t + 1024, FF, b_ff2, nullptr, bufA,
                nullptr, out, DD, 1024, DD / 128);
    }
}

// Round 19
// 1060.679 us; speedup vs baseline: 1.0688x; 1.0688x over previous
//
#include <hip/hip_runtime.h>

// ---------------- dims ----------------
#define BB 1024
#define NN 9
#define LL 81            // 81 cells
#define DD 512
#define HH 8
#define EE 64
#define FF 2048
#define MM (BB*LL)       // 82944 rows
#define N3 (3*DD)        // 1536

typedef unsigned short u16;
typedef __bf16 bf16x8 __attribute__((ext_vector_type(8)));
typedef float f32x4 __attribute__((ext_vector_type(4)));
typedef unsigned short u16x8 __attribute__((ext_vector_type(8)));

__device__ __forceinline__ float bf2f(u16 u) {
    return __uint_as_float(((unsigned int)u) << 16);
}
__device__ __forceinline__ u16 f2bf(float f) {
    unsigned int u = __float_as_uint(f);
    unsigned int r = u + 0x7fffu + ((u >> 16) & 1u);
    return (u16)(r >> 16);
}
// tanh-form GELU via manual exp-based tanh (~10 VALU ops; r10-proven)
__device__ __forceinline__ float gelu_fast(float x) {
    float u = 0.7978845608f * x * fmaf(0.044715f * x, x, 1.0f);
    float e = __expf(2.0f * u);
    float t = 1.0f - 2.0f / (e + 1.0f);
    return 0.5f * x * (1.0f + t);
}

// async global->LDS, 16B per lane
#define GL16(g, l) __builtin_amdgcn_global_load_lds( \
    (const __attribute__((address_space(1))) void*)(g), \
    (__attribute__((address_space(3))) void*)(l), 16, 0, 0)

#define SB0 __builtin_amdgcn_sched_barrier(0)

// ---------------- fused prologue: LN1 (blocks 0..20735) + 4 weight transposes ----------------
__global__ __launch_bounds__(256) void prep_k(
    const float* __restrict__ src, const float* __restrict__ g1,
    const float* __restrict__ beta1, u16* __restrict__ xln,
    const float* __restrict__ w_qkv, u16* __restrict__ wqkvt,
    const float* __restrict__ w_out, u16* __restrict__ woutt,
    const float* __restrict__ w_ff1, u16* __restrict__ wff1t,
    const float* __restrict__ w_ff2, u16* __restrict__ wff2t) {
    const int tid = threadIdx.x;
    int ib = blockIdx.x;
    if (ib < MM / 4) {
        // ---- LN1: 4 rows per block, one wave per 512-row ----
        int row = ib * 4 + (tid >> 6);
        int lane = tid & 63;
        const float4* xp = (const float4*)(src + (long)row * DD);
        float4 a = xp[lane * 2], b = xp[lane * 2 + 1];
        float s  = a.x + a.y + a.z + a.w + b.x + b.y + b.z + b.w;
        float sq = a.x*a.x + a.y*a.y + a.z*a.z + a.w*a.w
                 + b.x*b.x + b.y*b.y + b.z*b.z + b.w*b.w;
#pragma unroll
        for (int off = 1; off < 64; off <<= 1) {
            s  += __shfl_xor(s, off);
            sq += __shfl_xor(sq, off);
        }
        float mean = s * (1.0f / 512.0f);
        float var  = sq * (1.0f / 512.0f) - mean * mean;
        float rstd = rsqrtf(var + 1e-5f);
        const float4* gp = (const float4*)(g1 + lane * 8);
        const float4* bp = (const float4*)(beta1 + lane * 8);
        float4 g0 = gp[0], g1v = gp[1], b0 = bp[0], b1v = bp[1];
        float xv[8] = {a.x,a.y,a.z,a.w,b.x,b.y,b.z,b.w};
        float gv[8] = {g0.x,g0.y,g0.z,g0.w,g1v.x,g1v.y,g1v.z,g1v.w};
        float bv[8] = {b0.x,b0.y,b0.z,b0.w,b1v.x,b1v.y,b1v.z,b1v.w};
        u16x8 ov;
#pragma unroll
        for (int j = 0; j < 8; ++j)
            ov[j] = f2bf((xv[j] - mean) * rstd * gv[j] + bv[j]);
        *(u16x8*)(xln + (long)row * DD + lane * 8) = ov;
        return;
    }
    // ---- weight transpose + fp32->bf16: W (KxN) -> Wt (NxK) ----
    ib -= MM / 4;
    const float* W; u16* Wt; int K, N;
    if (ib < 768)        { W = w_qkv; Wt = wqkvt; K = DD; N = N3; }
    else if (ib < 1024)  { ib -= 768;  W = w_out; Wt = woutt; K = DD; N = DD; }
    else if (ib < 2048)  { ib -= 1024; W = w_ff1; Wt = wff1t; K = DD; N = FF; }
    else                 { ib -= 2048; W = w_ff2; Wt = wff2t; K = FF; N = DD; }
    __shared__ float t[32][33];
    const int nbx = N / 32;
    const int n0 = (ib % nbx) * 32, k0 = (ib / nbx) * 32;
    const int tx = tid & 31, ty = tid >> 5;  // 32 x 8
#pragma unroll
    for (int i = 0; i < 32; i += 8)
        t[ty + i][tx] = W[(long)(k0 + ty + i) * N + n0 + tx];
    __syncthreads();
#pragma unroll
    for (int i = 0; i < 32; i += 8)
        Wt[(long)(n0 + ty + i) * K + k0 + tx] = f2bf(t[tx][ty + i]);
}

// ---------------- layernorm bf16-in -> bf16 out ----------------
__global__ __launch_bounds__(256) void layernorm_b(const u16* __restrict__ X,
                                                   const float* __restrict__ g,
                                                   const float* __restrict__ be,
                                                   u16* __restrict__ Y) {
    int row = blockIdx.x * 4 + (threadIdx.x >> 6);
    int lane = threadIdx.x & 63;
    u16x8 xr = *(const u16x8*)(X + (long)row * DD + lane * 8);
    float xv[8];
#pragma unroll
    for (int j = 0; j < 8; ++j) xv[j] = bf2f(xr[j]);
    float s = 0.0f, sq = 0.0f;
#pragma unroll
    for (int j = 0; j < 8; ++j) { s += xv[j]; sq += xv[j] * xv[j]; }
#pragma unroll
    for (int off = 1; off < 64; off <<= 1) {
        s  += __shfl_xor(s, off);
        sq += __shfl_xor(sq, off);
    }
    float mean = s * (1.0f / 512.0f);
    float var  = sq * (1.0f / 512.0f) - mean * mean;
    float rstd = rsqrtf(var + 1e-5f);
    const float4* gp = (const float4*)(g + lane * 8);
    const float4* bp = (const float4*)(be + lane * 8);
    float4 g0 = gp[0], g1v = gp[1], b0 = bp[0], b1v = bp[1];
    float gv[8] = {g0.x,g0.y,g0.z,g0.w,g1v.x,g1v.y,g1v.z,g1v.w};
    float bv[8] = {b0.x,b0.y,b0.z,b0.w,b1v.x,b1v.y,b1v.z,b1v.w};
    u16x8 ov;
#pragma unroll
    for (int j = 0; j < 8; ++j)
        ov[j] = f2bf((xv[j] - mean) * rstd * gv[j] + bv[j]);
    *(u16x8*)(Y + (long)row * DD + lane * 8) = ov;
}

// ---------------- GEMM: C = A(bf16, MxK) @ Bt^T(bf16, NxK) ----------------
// r12/r16-proven best: block 256x128, 4 waves of 128x64 (16x16x32 MFMA). BK=32,
// 3-buffer stage-2-ahead, ONE barrier per K-step, counted vmcnt(6),
// conflict-free both-sides slot swizzle, XCD-chunked block swizzle,
// LDS-bounce epilogues (bf16 and fp32).
// NOTE: (256,2) only -- (256,3) spills the 128-AGPR accumulator (r11 disaster).
enum { EPI_BF16_BIAS = 0, EPI_BF16_RESID = 1, EPI_BF16_GELU = 2, EPI_F32_XADD = 3 };

template <int EPI>
__global__ __launch_bounds__(256, 2) void gemm_bt(
    const u16* __restrict__ A, int lda,
    const u16* __restrict__ Bt, int ldb,
    const float* __restrict__ bias,   // may be null
    const float* __restrict__ residF, // EPI_BF16_RESID: fp32 residual
    const u16* __restrict__ residB,   // EPI_F32_XADD: bf16 residual
    u16* __restrict__ outB, float* __restrict__ outF,
    int N, int K, int nbn) {
    __shared__ u16 smem[36864];            // 72KB: A 3x16KB + B 3x8KB; epilogue aliases
    u16* const Asb = smem;                 // A buf b at Asb + b*8192 (u16)
    u16* const Bsb = smem + 24576;         // B buf b at Bsb + b*4096 (u16)
    const int tid = threadIdx.x;
    const int lane = tid & 63;
    const int w = tid >> 6;
    const int wr = w >> 1, wc = w & 1;     // 2x2 waves; wave tile 128x64

    // bijective XCD-chunked swizzle (all launches have gridDim.x % 8 == 0)
    const int cpx = gridDim.x >> 3;
    const int bid = (blockIdx.x & 7) * cpx + (blockIdx.x >> 3);
    const int bm = bid / nbn, bn = bid % nbn;
    const long Arow0 = (long)bm * 256;
    const long Brow0 = (long)bn * 128;

    // stage one K-tile: A 256x32 (4 GL16/thr) + B 128x32 (2 GL16/thr). LDS dest
    // linear; global source chunk inverse-swizzled: LDS[row][s] = chunk s^((row>>1)&3).
    auto stage = [&](int buf, int kt) {
        const u16* abase = A + Arow0 * (long)lda + (long)kt * 32;
        const u16* bbase = Bt + Brow0 * (long)ldb + (long)kt * 32;
#pragma unroll
        for (int u = 0; u < 4; ++u) {
            const int c = tid + u * 256;       // 1024 A-chunks of 16B
            const int row = c >> 2;
            const int col = ((c & 3) ^ ((row >> 1) & 3)) * 8;
            GL16(abase + (long)row * lda + col, Asb + buf * 8192 + c * 8);
        }
#pragma unroll
        for (int u = 0; u < 2; ++u) {
            const int c = tid + u * 256;       // 512 B-chunks of 16B
            const int row = c >> 2;
            const int col = ((c & 3) ^ ((row >> 1) & 3)) * 8;
            GL16(bbase + (long)row * ldb + col, Bsb + buf * 4096 + c * 8);
        }
    };

    f32x4 acc[8][4] = {};
    const int fr = lane & 15;
    const int s8 = lane >> 4;
    const int sl = (s8 ^ ((fr >> 1) & 3)) * 8;  // conflict-free swizzled 16B slot

    const int nk = K / 32;                 // >= 16 for all our shapes
    stage(0, 0); stage(1, 1);              // 12 GL16/thread in flight

    int cur = 0;
    for (int kt = 0; kt < nk; ++kt) {
        // tile kt landed when <=6 younger loads outstanding (stage of kt+1)
        if (kt + 1 < nk) { asm volatile("s_waitcnt vmcnt(6)" ::: "memory"); }
        else             { asm volatile("s_waitcnt vmcnt(0)" ::: "memory"); }
        SB0;
        __builtin_amdgcn_s_barrier();      // publishes buf[cur]; orders prior reads
        SB0;

        bf16x8 af[8], bb[4];
        const u16* Ab = Asb + cur * 8192;
        const u16* Bb = Bsb + cur * 4096;
#pragma unroll
        for (int mt = 0; mt < 8; ++mt)
            af[mt] = *(const bf16x8*)(Ab + (wr * 128 + mt * 16 + fr) * 32 + sl);
#pragma unroll
        for (int nt = 0; nt < 4; ++nt)
            bb[nt] = *(const bf16x8*)(Bb + (wc * 64 + nt * 16 + fr) * 32 + sl);

        if (kt + 2 < nk) {                 // stage into buf last read at iter kt-1
            int nb = cur + 2; if (nb >= 3) nb -= 3;
            stage(nb, kt + 2);
        }

        asm volatile("s_waitcnt lgkmcnt(0)" ::: "memory");
        SB0;                               // rule #18: keep MFMAs below the wait
#pragma unroll
        for (int mt = 0; mt < 8; ++mt)
#pragma unroll
            for (int nt = 0; nt < 4; ++nt)
                acc[mt][nt] = __builtin_amdgcn_mfma_f32_16x16x32_bf16(af[mt], bb[nt], acc[mt][nt], 0, 0, 0);
        cur = cur + 1; if (cur == 3) cur = 0;
    }

    if (EPI == EPI_BF16_BIAS || EPI == EPI_BF16_GELU || EPI == EPI_BF16_RESID) {
        __builtin_amdgcn_s_barrier();      // all MFMA frag reads done before aliasing
        // LDS-bounce epilogue: 256x128 tile, pad stride 132, 16B coalesced stores
        u16 (*eps)[132] = (u16(*)[132])smem;
#pragma unroll
        for (int nt = 0; nt < 4; ++nt) {
            const int cl = wc * 64 + nt * 16 + fr;
            const float bv = bias ? bias[bn * 128 + cl] : 0.0f;
#pragma unroll
            for (int mt = 0; mt < 8; ++mt) {
                const int rl = wr * 128 + mt * 16 + s8 * 4;
#pragma unroll
                for (int q = 0; q < 4; ++q) {
                    float v = acc[mt][nt][q] + bv;
                    if (EPI == EPI_BF16_GELU) v = gelu_fast(v);
                    if (EPI == EPI_BF16_RESID)
                        v += residF[(Arow0 + rl + q) * (long)N + bn * 128 + cl];
                    eps[rl + q][cl] = f2bf(v);
                }
            }
        }
        __syncthreads();
#pragma unroll
        for (int u = 0; u < 16; ++u) {
            const int i = u * 256 + tid;
            const int row = i >> 4, cc = (i & 15) * 8;
            u16x8 vv = *(const u16x8*)&eps[row][cc];
            *(u16x8*)(outB + (Arow0 + row) * (long)N + bn * 128 + cc) = vv;
        }
    } else {  // EPI_F32_XADD: out = gemm + bias + bf16 residual, via fp32 LDS bounce
        float (*epf)[132] = (float(*)[132])smem;   // 128x132 f32 = 67.6KB <= 72KB
#pragma unroll
        for (int h = 0; h < 2; ++h) {
            __syncthreads();               // prior reads (K-loop / prev half) done
            if (wr == h) {
#pragma unroll
                for (int nt = 0; nt < 4; ++nt) {
                    const int cl = wc * 64 + nt * 16 + fr;
                    const float bv = bias ? bias[bn * 128 + cl] : 0.0f;
#pragma unroll
                    for (int mt = 0; mt < 8; ++mt) {
                        const int rl = mt * 16 + s8 * 4;    // local row in half
#pragma unroll
                        for (int q = 0; q < 4; ++q)
                            epf[rl + q][cl] = acc[mt][nt][q] + bv;
                    }
                }
            }
            __syncthreads();
            // coalesced float4 stores + ushort4 residual loads
#pragma unroll
            for (int u = 0; u < 16; ++u) {
                const int i = u * 256 + tid;          // 4096 chunks: 128 rows x 32
                const int row = i >> 5, cc = (i & 31) * 4;
                const long gr = (Arow0 + h * 128 + row) * (long)N + bn * 128 + cc;
                float4 vv = *(const float4*)&epf[row][cc];
                ushort4 rb = *(const ushort4*)(residB + gr);
                vv.x += bf2f(rb.x); vv.y += bf2f(rb.y);
                vv.z += bf2f(rb.z); vv.w += bf2f(rb.w);
                *(float4*)(outF + gr) = vv;
            }
        }
    }
}

// ---------------- factorized attention via MFMA: one block per (b, h) ----------------
// qkv: (B*L, 1536) bf16. y is written IN-PLACE into the q-slots (stride N3).
__global__ __launch_bounds__(256) void attn_k(u16* __restrict__ qkv) {
    __shared__ u16 S[96][104];    // bf16 scores
    __shared__ u16 Wm[96][104];   // bf16 combined softmax weights (cols 81..95 stay 0)
    __shared__ u16 Vt[64][104];   // V transposed: Vt[e][cell]
    const int bh = blockIdx.x;
    const int b = bh >> 3, h = bh & 7;
    u16* qbase = qkv + (long)b * LL * N3 + h * EE;
    const u16* kbase = qbase + DD;
    const u16* vbase = qbase + 2 * DD;
    const int tid = threadIdx.x;
    const int lane = tid & 63;
    const int w = tid >> 6;
    const int fr = lane & 15, s8 = lane >> 4;

    // phase 0a: zero Wm, zero Vt pad cols, scatter V -> Vt
    {
        u16x8 z = {};
        u16* wp = &Wm[0][0];
        for (int i = tid; i < (96 * 104) / 8; i += 256)
            *(u16x8*)(wp + i * 8) = z;
        for (int i = tid; i < 64 * 16; i += 256) {
            int e = i >> 4, c = i & 15;
            if (c < 15) Vt[e][81 + c] = 0;
        }
        for (int i = tid; i < 81 * 16; i += 256) {
            int cell = i >> 4, e0 = (i & 15) * 4;
            ushort4 v = *(const ushort4*)(vbase + (long)cell * N3 + e0);
            Vt[e0][cell] = v.x; Vt[e0 + 1][cell] = v.y;
            Vt[e0 + 2][cell] = v.z; Vt[e0 + 3][cell] = v.w;
        }
    }

    // phase 0b: QK^T -> S. 36 tiles of 16x16, K = 64; frags straight from global.
    for (int i = 0; i < 9; ++i) {
        const int tile = w + 4 * i;
        const int qt = tile / 6, kt = tile % 6;
        int qc = qt * 16 + fr; if (qc > 80) qc = 80;
        int kc = kt * 16 + fr; if (kc > 80) kc = 80;
        const u16* qp = qbase + (long)qc * N3 + s8 * 8;
        const u16* kp = kbase + (long)kc * N3 + s8 * 8;
        bf16x8 a0 = *(const bf16x8*)qp;
        bf16x8 a1 = *(const bf16x8*)(qp + 32);
        bf16x8 b0 = *(const bf16x8*)kp;
        bf16x8 b1 = *(const bf16x8*)(kp + 32);
        f32x4 acc = {};
        acc = __builtin_amdgcn_mfma_f32_16x16x32_bf16(a0, b0, acc, 0, 0, 0);
        acc = __builtin_amdgcn_mfma_f32_16x16x32_bf16(a1, b1, acc, 0, 0, 0);
#pragma unroll
        for (int q = 0; q < 4; ++q)
            S[qt * 16 + s8 * 4 + q][kt * 16 + fr] = f2bf(acc[q]);
    }
    __syncthreads();

    // phase 1: 3 softmaxes per query row, scatter-add into dense Wm row
    if (tid < 81) {
        const int q = tid;
        const int r = q / 9, c = q % 9;
#pragma unroll
        for (int t = 0; t < 3; ++t) {
            int mm[9];
            if (t == 0) {
#pragma unroll
                for (int j = 0; j < 9; ++j) mm[j] = r * 9 + j;
            } else if (t == 1) {
#pragma unroll
                for (int j = 0; j < 9; ++j) mm[j] = j * 9 + c;
            } else {
                const int br = (r / 3) * 3, bc = (c / 3) * 3;
#pragma unroll
                for (int j = 0; j < 9; ++j) mm[j] = (br + j / 3) * 9 + bc + j % 3;
            }
            float sc[9], mx = -1e30f;
#pragma unroll
            for (int j = 0; j < 9; ++j) {
                sc[j] = bf2f(S[q][mm[j]]) * 0.125f;
                mx = fmaxf(mx, sc[j]);
            }
            float sum = 0.0f;
#pragma unroll
            for (int j = 0; j < 9; ++j) { sc[j] = __expf(sc[j] - mx); sum += sc[j]; }
            const float inv = 1.0f / (3.0f * sum);
#pragma unroll
            for (int j = 0; j < 9; ++j) {
                u16* p = &Wm[q][mm[j]];
                *p = f2bf(bf2f(*p) + sc[j] * inv);
            }
        }
    }
    __syncthreads();

    // phase 2: Y^T = Vt(e,cell) @ Wm^T(cell,q); 8B stores into q-slots (stride N3)
    for (int i = 0; i < 6; ++i) {
        const int tile = w + 4 * i;
        const int qt = tile % 6, et = tile / 6;
        f32x4 acc = {};
#pragma unroll
        for (int kc = 0; kc < 3; ++kc) {
            bf16x8 a  = *(const bf16x8*)&Vt[et * 16 + fr][kc * 32 + s8 * 8];
            bf16x8 bf = *(const bf16x8*)&Wm[qt * 16 + fr][kc * 32 + s8 * 8];
            acc = __builtin_amdgcn_mfma_f32_16x16x32_bf16(a, bf, acc, 0, 0, 0);
        }
        const int q = qt * 16 + fr;
        if (q < 81) {
            ushort4 o;
            o.x = f2bf(acc[0]); o.y = f2bf(acc[1]);
            o.z = f2bf(acc[2]); o.w = f2bf(acc[3]);
            *(ushort4*)(qbase + (long)q * N3 + et * 16 + s8 * 4) = o;
        }
    }
}

// ---------------- launch ----------------
extern "C" void kernel_launch(void* const* d_in, const int* in_sizes, int n_in,
                              void* d_out, int out_size, void* d_ws, size_t ws_size,
                              hipStream_t stream) {
    const float* src    = (const float*)d_in[0];
    const float* w_qkv  = (const float*)d_in[1];
    const float* b_qkv  = (const float*)d_in[2];
    const float* w_out  = (const float*)d_in[3];
    const float* b_out  = (const float*)d_in[4];
    const float* g1     = (const float*)d_in[5];
    const float* beta1  = (const float*)d_in[6];
    const float* g2     = (const float*)d_in[7];
    const float* beta2  = (const float*)d_in[8];
    const float* w_ff1  = (const float*)d_in[9];
    const float* b_ff1  = (const float*)d_in[10];
    const float* w_ff2  = (const float*)d_in[11];
    const float* b_ff2  = (const float*)d_in[12];
    float* out = (float*)d_out;

    // workspace layout (bytes), all 256-aligned
    char* ws = (char*)d_ws;
    u16* wqkvt = (u16*)(ws + 0);                         // 1536x512 bf16
    u16* woutt = (u16*)(ws + 1572864);                   // 512x512
    u16* wff1t = (u16*)(ws + 2097152);                   // 2048x512
    u16* wff2t = (u16*)(ws + 4194304);                   // 512x2048
    u16* bufA  = (u16*)(ws + 6291456);                   // M x 512 bf16: xln -> xb
    u16* bufB  = (u16*)(ws + 6291456 + 84934656ULL);     // M x 1536 bf16: qkv/y -> hln + h1
    u16* hln   = bufB;                                   // M x 512 bf16 (LN2 out)
    u16* h1    = bufB + (size_t)MM * DD;                 // (M/2) x 2048 bf16 (GELU buf)

    const int nbm  = MM / 256;        // 324
    const int nbmh = (MM / 2) / 256;  // 162

    // 1) fused prologue: LN1 (20736 blocks) + all 4 weight transposes (3072 blocks)
    prep_k<<<MM / 4 + 3072, 256, 0, stream>>>(
        src, g1, beta1, bufA,
        w_qkv, wqkvt, w_out, woutt, w_ff1, wff1t, w_ff2, wff2t);

    // 2) qkv = xln @ Wqkv + b  (bf16 out, bufB)
    gemm_bt<EPI_BF16_BIAS><<<nbm * (N3 / 128), 256, 0, stream>>>(
        bufA, DD, wqkvt, DD, b_qkv, nullptr, nullptr, bufB, nullptr, N3, DD, N3 / 128);

    // 3) factorized attention; y overwrites the q-slots of bufB
    attn_k<<<BB * HH, 256, 0, stream>>>(bufB);

    // 4) xb = y @ Wout + b_out + src  (bf16, bufA; y read from bufB with lda=1536)
    gemm_bt<EPI_BF16_RESID><<<nbm * (DD / 128), 256, 0, stream>>>(
        bufB, N3, woutt, DD, b_out, src, nullptr, bufA, nullptr, DD, DD, DD / 128);

    // 5) LN2: xb -> hln (bufB head; qkv fully dead now)
    layernorm_b<<<MM / 4, 256, 0, stream>>>(bufA, g2, beta2, hln);

    // 6) FFN split by M-halves: h1 = gelu(hln@W1 + b1); out = h1@W2 + b2 + xb
    for (int mh = 0; mh < 2; ++mh) {
        const size_t roff = (size_t)mh * (MM / 2);
        gemm_bt<EPI_BF16_GELU><<<nbmh * (FF / 128), 256, 0, stream>>>(
            hln + roff * DD, DD, wff1t, DD, b_ff1, nullptr, nullptr,
            h1, nullptr, FF, DD, FF / 128);
        gemm_bt<EPI_F32_XADD><<<nbmh * (DD / 128), 256, 0, stream>>>(
            h1, FF, wff2t, FF, b_ff2, nullptr, bufA + roff * DD,
            nullptr, out + roff * DD, DD, FF, DD / 128);
    }
}